// Round 16
// baseline (335.646 us; speedup 1.0000x reference)
//
#include <hip/hip_runtime.h>
#include <hip/hip_bf16.h>
#include <math.h>

#define NHEAD 4
#define DHEAD 64
#define HD 256      // NHEAD*DHEAD
#define PDIM 32
#define LDH 288     // HD + PDIM, row stride of the persistent bf16 h buffer
#define NCB 17      // column blocks per k-block in packed weights (16 cols + 1 el/er)

typedef __attribute__((ext_vector_type(8))) short bf16x8;
typedef __attribute__((ext_vector_type(4))) float f32x4;
typedef __attribute__((ext_vector_type(2))) float f32x2;

static __device__ inline ushort f2bf(float f) {
  unsigned u = __float_as_uint(f);
  unsigned r = (u + 0x7fffu + ((u >> 16) & 1u)) >> 16;   // RTNE
  return (ushort)r;
}
static __device__ inline float bf2f(ushort s) {
  return __uint_as_float((unsigned)s << 16);
}

// ---------------- scans (CSR via excl + bsum, row_start computed inline) ----------------
__global__ void k_scan1(const int4* __restrict__ counts4, int4* __restrict__ sbase,
                        int* __restrict__ excl, int* __restrict__ bsum, int Nn) {
  __shared__ int buf[256];
  int b = blockIdx.x, t = threadIdx.x;
  int i = b * 256 + t;
  int tot = 0;
  if (i < Nn) {
    int4 c = counts4[i];
    int4 sb;
    sb.x = 0; sb.y = c.x; sb.z = c.x + c.y; sb.w = sb.z + c.z;
    tot = sb.w + c.w;
    sbase[i] = sb;
  }
  buf[t] = tot;
  __syncthreads();
  for (int off = 1; off < 256; off <<= 1) {
    int x = (t >= off) ? buf[t - off] : 0;
    __syncthreads();
    buf[t] += x;
    __syncthreads();
  }
  if (i <= Nn) excl[i] = buf[t] - tot;
  if (t == 255) bsum[b] = buf[255];
}

__global__ void k_scan2(int* __restrict__ bsum, int nb) {
  __shared__ int buf[256];
  int t = threadIdx.x;
  int v = (t < nb) ? bsum[t] : 0;
  buf[t] = v;
  __syncthreads();
  for (int off = 1; off < 256; off <<= 1) {
    int x = (t >= off) ? buf[t - off] : 0;
    __syncthreads();
    buf[t] += x;
    __syncthreads();
  }
  if (t < nb) bsum[t] = buf[t] - v;   // exclusive
}

// ---------------- merged prep: edge count FIRST, then h0 assembly + weight pack ------
struct PackArgs {
  const float* W[6];    // W0,rW0,W1,rW1,W2,rW2
  const float* al[6];   // al_L for W slots, null for rW slots
  const float* ar[6];
  int kboff[7];         // cumulative kb (K/32) offsets
};

__global__ void k_prep(const float* __restrict__ fvs, const float* __restrict__ pe,
                       ushort* __restrict__ hbuf, int Nn, int nbCnt, int nbH0,
                       PackArgs pa, ushort* __restrict__ Bp,
                       const int* __restrict__ dst, int* __restrict__ counts4,
                       int* __restrict__ rank, int E) {
  int bx = blockIdx.x;
  if (bx < nbCnt) {
    // region 1 (FIRST -> scheduled earliest): edge count, 4 edges/thread grid-stride
    int stride = nbCnt * 256;
    for (int i = bx * 256 + threadIdx.x; i < E; i += stride) {
      int d = dst[i];
      rank[i] = atomicAdd(&counts4[(d << 2) | (i & 3)], 1);
    }
    return;
  }
  bx -= nbCnt;
  if (bx < nbH0) {
    // region 2: layer-0 input assembly
    int i = bx * 256 + threadIdx.x;
    int total = Nn * 20;            // 160/8
    if (i >= total) return;
    int n = i / 20, j8 = (i - n * 20) * 8;
    const float* srcp = (j8 < 128) ? &fvs[n * 128 + j8] : &pe[n * PDIM + (j8 - 128)];
    float4 a = *(const float4*)srcp;
    float4 b = *(const float4*)(srcp + 4);
    ushort o[8] = {f2bf(a.x), f2bf(a.y), f2bf(a.z), f2bf(a.w),
                   f2bf(b.x), f2bf(b.y), f2bf(b.z), f2bf(b.w)};
    *(uint4*)&hbuf[(size_t)n * LDH + j8] = *(uint4*)o;
    return;
  }
  // region 3: weight pack
  int i = (bx - nbH0) * 256 + threadIdx.x;
  int total = pa.kboff[6] * NCB * 64;
  if (i >= total) return;
  int lane = i & 63;
  int cb = (i >> 6) % NCB;
  int kbg = i / (NCB * 64);
  int m = 0;
  while (kbg >= pa.kboff[m + 1]) ++m;
  int kb = kbg - pa.kboff[m];
  const float* W = pa.W[m];
  int kbase = kb * 32 + (lane >> 4) * 8;
  ushort v[8];
  if (cb < 16) {
    int col = cb * 16 + (lane & 15);
#pragma unroll
    for (int j = 0; j < 8; ++j) v[j] = f2bf(W[(size_t)(kbase + j) * HD + col]);
  } else {
    int c = lane & 15;
    const float* a = (c < 4) ? pa.al[m] : ((c < 8) ? pa.ar[m] : nullptr);
    int h = c & 3;
#pragma unroll
    for (int j = 0; j < 8; ++j) {
      float s = 0.f;
      if (a) {
        const float* wr = &W[(size_t)(kbase + j) * HD + h * 64];
        const float* av = &a[h * 64];
        for (int d = 0; d < 64; ++d) s = fmaf(wr[d], av[d], s);
      }
      v[j] = f2bf(s);
    }
  }
  *(uint4*)&Bp[(size_t)i * 8] = *(uint4*)v;
}

// ---------------- MFMA GEMM (R11 frozen form) + fused scatter blocks --------------
template <int NKB>
__global__ __launch_bounds__(256) void k_gemm(const ushort* __restrict__ X,
                                              const ushort* __restrict__ BpW,
                                              const ushort* __restrict__ BprW,
                                              unsigned char* __restrict__ featf8,
                                              ushort* __restrict__ rrb,
                                              float* __restrict__ el,
                                              float* __restrict__ er,
                                              int Nn, int gb,
                                              const int* __restrict__ src,
                                              const int* __restrict__ dst,
                                              const int* __restrict__ rank,
                                              const int* __restrict__ excl,
                                              const int* __restrict__ bsum,
                                              const int4* __restrict__ sbase,
                                              int* __restrict__ esrc, int E) {
  __shared__ float lds[4][16 * 68];
  if ((int)blockIdx.x >= gb) {
    // scatter region (split across the two grid.y halves)
    int e = blockIdx.x - gb;
    int i = (e * 2 + blockIdx.y) * 256 + threadIdx.x;
    if (i < E) {
      int d = dst[i];
      int4 sb = sbase[d];
      int s = i & 3;
      int so = (s == 0) ? sb.x : (s == 1) ? sb.y : (s == 2) ? sb.z : sb.w;
      esrc[excl[d] + bsum[d >> 8] + so + rank[i]] = src[i];
    }
    return;
  }

  int t = threadIdx.x;
  int w = t >> 6, lane = t & 63;
  int mode = blockIdx.y;
  const ushort* Bp = mode ? BprW : BpW;
  int row0 = blockIdx.x * 64;
  int col0 = (w & 3) * 64;
  int lr = lane & 15, lk = lane >> 4;
  bool do_e = (mode == 0) && (w == 0);

  int arow[4];
#pragma unroll
  for (int m = 0; m < 4; ++m) {
    int r = row0 + m * 16 + lr;
    arow[m] = (r < Nn) ? r : (Nn - 1);
  }

  f32x4 acc[4][4] = {};
  f32x4 acce[4] = {};
  int cb0 = col0 >> 4;
#pragma unroll
  for (int kb = 0; kb < NKB; ++kb) {
    int k0 = kb * 32;
    bf16x8 a[4], b[4];
#pragma unroll
    for (int m = 0; m < 4; ++m)
      a[m] = *(const bf16x8*)&X[(size_t)arow[m] * LDH + k0 + lk * 8];
#pragma unroll
    for (int n = 0; n < 4; ++n)
      b[n] = *(const bf16x8*)&Bp[(((size_t)kb * NCB + cb0 + n) * 64 + lane) * 8];
#pragma unroll
    for (int m = 0; m < 4; ++m)
#pragma unroll
      for (int n = 0; n < 4; ++n)
        acc[m][n] = __builtin_amdgcn_mfma_f32_16x16x32_bf16(a[m], b[n], acc[m][n], 0, 0, 0);
    if (do_e) {
      bf16x8 be = *(const bf16x8*)&Bp[(((size_t)kb * NCB + 16) * 64 + lane) * 8];
#pragma unroll
      for (int m = 0; m < 4; ++m)
        acce[m] = __builtin_amdgcn_mfma_f32_16x16x32_bf16(a[m], be, acce[m], 0, 0, 0);
    }
  }

  if (do_e) {
    int c = lane & 15;
#pragma unroll
    for (int m = 0; m < 4; ++m)
#pragma unroll
      for (int reg = 0; reg < 4; ++reg) {
        int row = row0 + m * 16 + (lane >> 4) * 4 + reg;
        if (row < Nn) {
          if (c < 4) el[row * NHEAD + c] = acce[m][reg];
          else if (c < 8) er[row * NHEAD + (c - 4)] = acce[m][reg];
        }
      }
  }

  // store via per-wave LDS transpose for coalesced writes
  float* L = &lds[w][0];
  int r16 = lane >> 2, cbase = (lane & 3) * 16;
#pragma unroll
  for (int m = 0; m < 4; ++m) {
#pragma unroll
    for (int n = 0; n < 4; ++n)
#pragma unroll
      for (int reg = 0; reg < 4; ++reg)
        L[((lane >> 4) * 4 + reg) * 68 + n * 16 + (lane & 15)] = acc[m][n][reg];
    __syncthreads();
    int row = row0 + m * 16 + r16;
    if (row < Nn) {
      float c[16];
#pragma unroll
      for (int j = 0; j < 16; ++j) c[j] = L[r16 * 68 + cbase + j];
      if (mode == 0) {
        unsigned d[4];
#pragma unroll
        for (int q = 0; q < 4; ++q) {
          unsigned v = 0;
          v = __builtin_amdgcn_cvt_pk_fp8_f32(c[q * 4 + 0], c[q * 4 + 1], v, false);
          v = __builtin_amdgcn_cvt_pk_fp8_f32(c[q * 4 + 2], c[q * 4 + 3], v, true);
          d[q] = v;
        }
        *(uint4*)&featf8[(size_t)row * HD + col0 + cbase] = make_uint4(d[0], d[1], d[2], d[3]);
      } else {
        ushort tmp[16];
#pragma unroll
        for (int j = 0; j < 16; ++j) tmp[j] = f2bf(c[j]);
        *(uint4*)&rrb[(size_t)row * HD + col0 + cbase] = *(uint4*)&tmp[0];
        *(uint4*)&rrb[(size_t)row * HD + col0 + cbase + 8] = *(uint4*)&tmp[8];
      }
    }
    __syncthreads();
  }
}

// ---------------- edge softmax + aggregate + residual + elu (rrb hoisted) ----
__global__ __launch_bounds__(256) void k_agg(const int* __restrict__ esrc,
                                             const int* __restrict__ excl,
                                             const int* __restrict__ bsum,
                                             const float* __restrict__ el,
                                             const float* __restrict__ er,
                                             const unsigned char* __restrict__ featf8,
                                             const ushort* __restrict__ rrb,
                                             const float* __restrict__ pe,
                                             ushort* __restrict__ hnext,
                                             float* __restrict__ out,
                                             int last, int Nn) {
  int w = threadIdx.x >> 6;
  int lane = threadIdx.x & 63;
  int n = blockIdx.x * 4 + w;
  if (n >= Nn) return;
  int g = lane >> 4;        // group 0..3 (edge-parallel)
  int l = lane & 15;        // lane within group: cols [l*16, l*16+16)
  int h = l >> 2;           // head of these 16 cols
  int beg = excl[n] + bsum[n >> 8];
  int end = excl[n + 1] + bsum[(n + 1) >> 8];
  float ern = er[n * NHEAD + h];

  // independent load issued before the edge loop (latency hides under the loop)
  ushort rv[16];
  *(uint4*)&rv[0] = *(const uint4*)&rrb[(size_t)n * HD + l * 16];
  *(uint4*)&rv[8] = *(const uint4*)&rrb[(size_t)n * HD + l * 16 + 8];

  f32x2 acc2[8] = {};
  float dn = 0.f;
#define DEC8(uu, q, wv)                                                       \
    {                                                                         \
      f32x2 f0 = __builtin_amdgcn_cvt_pk_f32_fp8((int)(uu), false);           \
      f32x2 f1 = __builtin_amdgcn_cvt_pk_f32_fp8((int)(uu), true);            \
      acc2[2 * q]     = __builtin_elementwise_fma(wv, f0, acc2[2 * q]);       \
      acc2[2 * q + 1] = __builtin_elementwise_fma(wv, f1, acc2[2 * q + 1]);   \
    }
  int p = beg + g;
  for (; p + 4 < end; p += 8) {
    int s0 = esrc[p], s1 = esrc[p + 4];
    float lg0 = el[s0 * NHEAD + h] + ern;
    float lg1 = el[s1 * NHEAD + h] + ern;
    lg0 = (lg0 > 0.f) ? lg0 : 0.2f * lg0;
    lg1 = (lg1 > 0.f) ? lg1 : 0.2f * lg1;
    float w0 = __expf(lg0), w1 = __expf(lg1);
    dn += w0 + w1;
    f32x2 wv0 = {w0, w0}, wv1 = {w1, w1};
    uint4 u0 = *(const uint4*)(featf8 + (size_t)s0 * HD + l * 16);
    uint4 u1 = *(const uint4*)(featf8 + (size_t)s1 * HD + l * 16);
    DEC8(u0.x, 0, wv0) DEC8(u0.y, 1, wv0) DEC8(u0.z, 2, wv0) DEC8(u0.w, 3, wv0)
    DEC8(u1.x, 0, wv1) DEC8(u1.y, 1, wv1) DEC8(u1.z, 2, wv1) DEC8(u1.w, 3, wv1)
  }
  if (p < end) {
    int s0 = esrc[p];
    float lg0 = el[s0 * NHEAD + h] + ern;
    lg0 = (lg0 > 0.f) ? lg0 : 0.2f * lg0;
    float w0 = __expf(lg0);
    dn += w0;
    f32x2 wv0 = {w0, w0};
    uint4 u0 = *(const uint4*)(featf8 + (size_t)s0 * HD + l * 16);
    DEC8(u0.x, 0, wv0) DEC8(u0.y, 1, wv0) DEC8(u0.z, 2, wv0) DEC8(u0.w, 3, wv0)
  }
#undef DEC8
  dn += __shfl_xor(dn, 16);
  dn += __shfl_xor(dn, 32);
  float accs[16];
#pragma unroll
  for (int j = 0; j < 16; ++j) {
    float s = acc2[j >> 1][j & 1];
    s += __shfl_xor(s, 16);
    s += __shfl_xor(s, 32);
    accs[j] = s;
  }

  bool has = (end > beg);
  float vres[16];
  float inv = has ? 1.f / dn : 0.f;
#pragma unroll
  for (int j = 0; j < 16; ++j) {
    float v = accs[j] * inv + bf2f(rv[j]);
    vres[j] = (v > 0.f) ? v : (__expf(v) - 1.f);   // elu
  }

  if (!last) {
    if (g == 0) {
      ushort o[16];
#pragma unroll
      for (int j = 0; j < 16; ++j) o[j] = f2bf(vres[j]);
      *(uint4*)&hnext[(size_t)n * LDH + l * 16] = *(uint4*)&o[0];
      *(uint4*)&hnext[(size_t)n * LDH + l * 16 + 8] = *(uint4*)&o[8];
      if (l < 2) {
        ushort o2[16];
#pragma unroll
        for (int j = 0; j < 16; ++j) o2[j] = f2bf(pe[n * PDIM + l * 16 + j]);
        *(uint4*)&hnext[(size_t)n * LDH + HD + l * 16] = *(uint4*)&o2[0];
        *(uint4*)&hnext[(size_t)n * LDH + HD + l * 16 + 8] = *(uint4*)&o2[8];
      }
    }
  } else {
#pragma unroll
    for (int j = 0; j < 16; ++j) {
      vres[j] += __shfl_xor(vres[j], 4);
      vres[j] += __shfl_xor(vres[j], 8);
      vres[j] *= 0.25f;
    }
    if (g == 0 && l < 4) {
#pragma unroll
      for (int q = 0; q < 4; ++q)
        *(float4*)&out[(size_t)n * DHEAD + l * 16 + q * 4] =
            make_float4(vres[q * 4], vres[q * 4 + 1], vres[q * 4 + 2], vres[q * 4 + 3]);
    }
    if (g == 0 && l >= 4 && l < 6) {
      int c0 = (l - 4) * 16;
#pragma unroll
      for (int q = 0; q < 4; ++q) {
        const float* ps = &pe[n * PDIM + c0 + q * 4];
        *(float4*)&out[(size_t)Nn * DHEAD + (size_t)n * PDIM + c0 + q * 4] =
            make_float4(ps[0], ps[1], ps[2], ps[3]);
      }
    }
  }
}

extern "C" void kernel_launch(void* const* d_in, const int* in_sizes, int n_in,
                              void* d_out, int out_size, void* d_ws, size_t ws_size,
                              hipStream_t stream) {
  const float* fvs = (const float*)d_in[0];
  const float* pe  = (const float*)d_in[1];
  const int* src = (const int*)d_in[2];
  const int* dst = (const int*)d_in[3];
  const float* W[3]  = {(const float*)d_in[4], (const float*)d_in[8],  (const float*)d_in[12]};
  const float* al[3] = {(const float*)d_in[5], (const float*)d_in[9],  (const float*)d_in[13]};
  const float* ar[3] = {(const float*)d_in[6], (const float*)d_in[10], (const float*)d_in[14]};
  const float* rW[3] = {(const float*)d_in[7], (const float*)d_in[11], (const float*)d_in[15]};
  int Nn = in_sizes[0] / 128;
  int E  = in_sizes[2];
  int Ks[3] = {160, 288, 288};
  int nb1 = (Nn + 1 + 255) / 256;   // scan covers Nn+1 elements

  char* ws = (char*)d_ws;
  size_t off = 0;
  auto alloc = [&](size_t bytes) {
    void* p = ws + off;
    off += (bytes + 255) & ~(size_t)255;
    return p;
  };
  ushort* hbuf  = (ushort*)alloc((size_t)Nn * LDH * 2);
  unsigned char* featf8 = (unsigned char*)alloc((size_t)Nn * HD);
  ushort* rrb = (ushort*)alloc((size_t)Nn * HD * 2);
  float* el   = (float*)alloc((size_t)Nn * NHEAD * 4);
  float* er   = (float*)alloc((size_t)Nn * NHEAD * 4);
  PackArgs pa;
  int kbs[6] = {5, 5, 9, 9, 9, 9};
  pa.kboff[0] = 0;
  for (int m = 0; m < 6; ++m) pa.kboff[m + 1] = pa.kboff[m] + kbs[m];
  pa.W[0] = W[0]; pa.W[1] = rW[0]; pa.W[2] = W[1]; pa.W[3] = rW[1]; pa.W[4] = W[2]; pa.W[5] = rW[2];
  pa.al[0] = al[0]; pa.al[1] = nullptr; pa.al[2] = al[1]; pa.al[3] = nullptr; pa.al[4] = al[2]; pa.al[5] = nullptr;
  pa.ar[0] = ar[0]; pa.ar[1] = nullptr; pa.ar[2] = ar[1]; pa.ar[3] = nullptr; pa.ar[4] = ar[2]; pa.ar[5] = nullptr;
  ushort* Bp = (ushort*)alloc((size_t)pa.kboff[6] * NCB * 64 * 8 * 2);
  int* counts4   = (int*)alloc((size_t)Nn * 4 * 4);
  int4* sbase    = (int4*)alloc((size_t)Nn * 16);
  int* rank      = (int*)alloc((size_t)E * 4);
  int* excl      = (int*)alloc((size_t)(Nn + 1) * 4);
  int* bsum      = (int*)alloc((size_t)256 * 4);
  int* esrc      = (int*)alloc((size_t)E * 4);

  hipMemsetAsync(counts4, 0, (size_t)Nn * 16, stream);
  int nbCnt = (E + 1023) / 1024;    // 4 edges per thread, grid-stride
  int nbH0 = (Nn * 20 + 255) / 256;
  int nbPk = (pa.kboff[6] * NCB * 64 + 255) / 256;
  k_prep<<<nbCnt + nbH0 + nbPk, 256, 0, stream>>>(fvs, pe, hbuf, Nn, nbCnt, nbH0,
                                                  pa, Bp, dst, counts4, rank, E);
  k_scan1<<<nb1, 256, 0, stream>>>((const int4*)counts4, sbase, excl, bsum, Nn);
  k_scan2<<<1, 256, 0, stream>>>(bsum, nb1);

  float* out = (float*)d_out;
  int gb = (Nn + 63) / 64;
  int nbScat = (E + 255) / 256;
  int nbSc = (nbScat + 1) / 2;      // scatter blocks per grid.y half
  for (int L = 0; L < 3; ++L) {
    const ushort* BpW  = Bp + (size_t)pa.kboff[2 * L] * NCB * 64 * 8;
    const ushort* BprW = Bp + (size_t)pa.kboff[2 * L + 1] * NCB * 64 * 8;
    dim3 g(L == 0 ? gb + nbSc : gb, 2);
    if (Ks[L] == 160)
      k_gemm<5><<<g, 256, 0, stream>>>(hbuf, BpW, BprW, featf8, rrb, el, er, Nn, gb,
                                       src, dst, rank, excl, bsum, sbase, esrc, E);
    else
      k_gemm<9><<<g, 256, 0, stream>>>(hbuf, BpW, BprW, featf8, rrb, el, er, Nn, gb,
                                       src, dst, rank, excl, bsum, sbase, esrc, E);
    int last = (L == 2) ? 1 : 0;
    k_agg<<<(Nn + 3) / 4, 256, 0, stream>>>(esrc, excl, bsum, el, er, featf8, rrb, pe,
                                            hbuf, out, last, Nn);
  }
}

// Round 17
// 322.214 us; speedup vs baseline: 1.0417x; 1.0417x over previous
//
#include <hip/hip_runtime.h>
#include <hip/hip_bf16.h>
#include <math.h>

#define NHEAD 4
#define DHEAD 64
#define HD 256      // NHEAD*DHEAD
#define PDIM 32
#define LDH 288     // HD + PDIM, row stride of the persistent bf16 h buffer
#define NCB 17      // column blocks per k-block in packed weights (16 cols + 1 el/er)

typedef __attribute__((ext_vector_type(8))) short bf16x8;
typedef __attribute__((ext_vector_type(4))) float f32x4;
typedef __attribute__((ext_vector_type(2))) float f32x2;

static __device__ inline ushort f2bf(float f) {
  unsigned u = __float_as_uint(f);
  unsigned r = (u + 0x7fffu + ((u >> 16) & 1u)) >> 16;   // RTNE
  return (ushort)r;
}
static __device__ inline float bf2f(ushort s) {
  return __uint_as_float((unsigned)s << 16);
}

// ---------------- scans (CSR via excl + bsum, row_start computed inline) ----------------
__global__ void k_scan1(const int4* __restrict__ counts4, int4* __restrict__ sbase,
                        int* __restrict__ excl, int* __restrict__ bsum, int Nn) {
  __shared__ int buf[256];
  int b = blockIdx.x, t = threadIdx.x;
  int i = b * 256 + t;
  int tot = 0;
  if (i < Nn) {
    int4 c = counts4[i];
    int4 sb;
    sb.x = 0; sb.y = c.x; sb.z = c.x + c.y; sb.w = sb.z + c.z;
    tot = sb.w + c.w;
    sbase[i] = sb;
  }
  buf[t] = tot;
  __syncthreads();
  for (int off = 1; off < 256; off <<= 1) {
    int x = (t >= off) ? buf[t - off] : 0;
    __syncthreads();
    buf[t] += x;
    __syncthreads();
  }
  if (i <= Nn) excl[i] = buf[t] - tot;
  if (t == 255) bsum[b] = buf[255];
}

__global__ void k_scan2(int* __restrict__ bsum, int nb) {
  __shared__ int buf[256];
  int t = threadIdx.x;
  int v = (t < nb) ? bsum[t] : 0;
  buf[t] = v;
  __syncthreads();
  for (int off = 1; off < 256; off <<= 1) {
    int x = (t >= off) ? buf[t - off] : 0;
    __syncthreads();
    buf[t] += x;
    __syncthreads();
  }
  if (t < nb) bsum[t] = buf[t] - v;   // exclusive
}

// ---------------- merged prep: edge count FIRST, then h0 assembly + weight pack ------
struct PackArgs {
  const float* W[6];    // W0,rW0,W1,rW1,W2,rW2
  const float* al[6];   // al_L for W slots, null for rW slots
  const float* ar[6];
  int kboff[7];         // cumulative kb (K/32) offsets
};

__global__ void k_prep(const float* __restrict__ fvs, const float* __restrict__ pe,
                       ushort* __restrict__ hbuf, int Nn, int nbCnt, int nbH0,
                       PackArgs pa, ushort* __restrict__ Bp,
                       const int* __restrict__ dst, int* __restrict__ counts4,
                       int* __restrict__ rank, int E) {
  int bx = blockIdx.x;
  if (bx < nbCnt) {
    // region 1 (FIRST -> scheduled earliest): edge count, 4 edges/thread grid-stride
    int stride = nbCnt * 256;
    for (int i = bx * 256 + threadIdx.x; i < E; i += stride) {
      int d = dst[i];
      rank[i] = atomicAdd(&counts4[(d << 2) | (i & 3)], 1);
    }
    return;
  }
  bx -= nbCnt;
  if (bx < nbH0) {
    // region 2: layer-0 input assembly
    int i = bx * 256 + threadIdx.x;
    int total = Nn * 20;            // 160/8
    if (i >= total) return;
    int n = i / 20, j8 = (i - n * 20) * 8;
    const float* srcp = (j8 < 128) ? &fvs[n * 128 + j8] : &pe[n * PDIM + (j8 - 128)];
    float4 a = *(const float4*)srcp;
    float4 b = *(const float4*)(srcp + 4);
    ushort o[8] = {f2bf(a.x), f2bf(a.y), f2bf(a.z), f2bf(a.w),
                   f2bf(b.x), f2bf(b.y), f2bf(b.z), f2bf(b.w)};
    *(uint4*)&hbuf[(size_t)n * LDH + j8] = *(uint4*)o;
    return;
  }
  // region 3: weight pack
  int i = (bx - nbH0) * 256 + threadIdx.x;
  int total = pa.kboff[6] * NCB * 64;
  if (i >= total) return;
  int lane = i & 63;
  int cb = (i >> 6) % NCB;
  int kbg = i / (NCB * 64);
  int m = 0;
  while (kbg >= pa.kboff[m + 1]) ++m;
  int kb = kbg - pa.kboff[m];
  const float* W = pa.W[m];
  int kbase = kb * 32 + (lane >> 4) * 8;
  ushort v[8];
  if (cb < 16) {
    int col = cb * 16 + (lane & 15);
#pragma unroll
    for (int j = 0; j < 8; ++j) v[j] = f2bf(W[(size_t)(kbase + j) * HD + col]);
  } else {
    int c = lane & 15;
    const float* a = (c < 4) ? pa.al[m] : ((c < 8) ? pa.ar[m] : nullptr);
    int h = c & 3;
#pragma unroll
    for (int j = 0; j < 8; ++j) {
      float s = 0.f;
      if (a) {
        const float* wr = &W[(size_t)(kbase + j) * HD + h * 64];
        const float* av = &a[h * 64];
        for (int d = 0; d < 64; ++d) s = fmaf(wr[d], av[d], s);
      }
      v[j] = f2bf(s);
    }
  }
  *(uint4*)&Bp[(size_t)i * 8] = *(uint4*)v;
}

// ---------------- MFMA GEMM (R11 frozen form) + fused scatter blocks --------------
template <int NKB>
__global__ __launch_bounds__(256) void k_gemm(const ushort* __restrict__ X,
                                              const ushort* __restrict__ BpW,
                                              const ushort* __restrict__ BprW,
                                              unsigned char* __restrict__ featf8,
                                              ushort* __restrict__ rrb,
                                              float* __restrict__ el,
                                              float* __restrict__ er,
                                              int Nn, int gb,
                                              const int* __restrict__ src,
                                              const int* __restrict__ dst,
                                              const int* __restrict__ rank,
                                              const int* __restrict__ excl,
                                              const int* __restrict__ bsum,
                                              const int4* __restrict__ sbase,
                                              int* __restrict__ esrc, int E) {
  __shared__ float lds[4][16 * 68];
  if ((int)blockIdx.x >= gb) {
    // scatter region (split across the two grid.y halves)
    int e = blockIdx.x - gb;
    int i = (e * 2 + blockIdx.y) * 256 + threadIdx.x;
    if (i < E) {
      int d = dst[i];
      int4 sb = sbase[d];
      int s = i & 3;
      int so = (s == 0) ? sb.x : (s == 1) ? sb.y : (s == 2) ? sb.z : sb.w;
      esrc[excl[d] + bsum[d >> 8] + so + rank[i]] = src[i];
    }
    return;
  }

  int t = threadIdx.x;
  int w = t >> 6, lane = t & 63;
  int mode = blockIdx.y;
  const ushort* Bp = mode ? BprW : BpW;
  int row0 = blockIdx.x * 64;
  int col0 = (w & 3) * 64;
  int lr = lane & 15, lk = lane >> 4;
  bool do_e = (mode == 0) && (w == 0);

  int arow[4];
#pragma unroll
  for (int m = 0; m < 4; ++m) {
    int r = row0 + m * 16 + lr;
    arow[m] = (r < Nn) ? r : (Nn - 1);
  }

  f32x4 acc[4][4] = {};
  f32x4 acce[4] = {};
  int cb0 = col0 >> 4;
#pragma unroll
  for (int kb = 0; kb < NKB; ++kb) {
    int k0 = kb * 32;
    bf16x8 a[4], b[4];
#pragma unroll
    for (int m = 0; m < 4; ++m)
      a[m] = *(const bf16x8*)&X[(size_t)arow[m] * LDH + k0 + lk * 8];
#pragma unroll
    for (int n = 0; n < 4; ++n)
      b[n] = *(const bf16x8*)&Bp[(((size_t)kb * NCB + cb0 + n) * 64 + lane) * 8];
#pragma unroll
    for (int m = 0; m < 4; ++m)
#pragma unroll
      for (int n = 0; n < 4; ++n)
        acc[m][n] = __builtin_amdgcn_mfma_f32_16x16x32_bf16(a[m], b[n], acc[m][n], 0, 0, 0);
    if (do_e) {
      bf16x8 be = *(const bf16x8*)&Bp[(((size_t)kb * NCB + 16) * 64 + lane) * 8];
#pragma unroll
      for (int m = 0; m < 4; ++m)
        acce[m] = __builtin_amdgcn_mfma_f32_16x16x32_bf16(a[m], be, acce[m], 0, 0, 0);
    }
  }

  if (do_e) {
    int c = lane & 15;
#pragma unroll
    for (int m = 0; m < 4; ++m)
#pragma unroll
      for (int reg = 0; reg < 4; ++reg) {
        int row = row0 + m * 16 + (lane >> 4) * 4 + reg;
        if (row < Nn) {
          if (c < 4) el[row * NHEAD + c] = acce[m][reg];
          else if (c < 8) er[row * NHEAD + (c - 4)] = acce[m][reg];
        }
      }
  }

  // store via per-wave LDS transpose for coalesced writes
  float* L = &lds[w][0];
  int r16 = lane >> 2, cbase = (lane & 3) * 16;
#pragma unroll
  for (int m = 0; m < 4; ++m) {
#pragma unroll
    for (int n = 0; n < 4; ++n)
#pragma unroll
      for (int reg = 0; reg < 4; ++reg)
        L[((lane >> 4) * 4 + reg) * 68 + n * 16 + (lane & 15)] = acc[m][n][reg];
    __syncthreads();
    int row = row0 + m * 16 + r16;
    if (row < Nn) {
      float c[16];
#pragma unroll
      for (int j = 0; j < 16; ++j) c[j] = L[r16 * 68 + cbase + j];
      if (mode == 0) {
        unsigned d[4];
#pragma unroll
        for (int q = 0; q < 4; ++q) {
          unsigned v = 0;
          v = __builtin_amdgcn_cvt_pk_fp8_f32(c[q * 4 + 0], c[q * 4 + 1], v, false);
          v = __builtin_amdgcn_cvt_pk_fp8_f32(c[q * 4 + 2], c[q * 4 + 3], v, true);
          d[q] = v;
        }
        *(uint4*)&featf8[(size_t)row * HD + col0 + cbase] = make_uint4(d[0], d[1], d[2], d[3]);
      } else {
        ushort tmp[16];
#pragma unroll
        for (int j = 0; j < 16; ++j) tmp[j] = f2bf(c[j]);
        *(uint4*)&rrb[(size_t)row * HD + col0 + cbase] = *(uint4*)&tmp[0];
        *(uint4*)&rrb[(size_t)row * HD + col0 + cbase + 8] = *(uint4*)&tmp[8];
      }
    }
    __syncthreads();
  }
}

// ---------------- edge softmax + aggregate + residual + elu (R10 frozen form) ----
__global__ __launch_bounds__(256) void k_agg(const int* __restrict__ esrc,
                                             const int* __restrict__ excl,
                                             const int* __restrict__ bsum,
                                             const float* __restrict__ el,
                                             const float* __restrict__ er,
                                             const unsigned char* __restrict__ featf8,
                                             const ushort* __restrict__ rrb,
                                             const float* __restrict__ pe,
                                             ushort* __restrict__ hnext,
                                             float* __restrict__ out,
                                             int last, int Nn) {
  int w = threadIdx.x >> 6;
  int lane = threadIdx.x & 63;
  int n = blockIdx.x * 4 + w;
  if (n >= Nn) return;
  int g = lane >> 4;        // group 0..3 (edge-parallel)
  int l = lane & 15;        // lane within group: cols [l*16, l*16+16)
  int h = l >> 2;           // head of these 16 cols
  int beg = excl[n] + bsum[n >> 8];
  int end = excl[n + 1] + bsum[(n + 1) >> 8];
  float ern = er[n * NHEAD + h];

  f32x2 acc2[8] = {};
  float dn = 0.f;
#define DEC8(uu, q, wv)                                                       \
    {                                                                         \
      f32x2 f0 = __builtin_amdgcn_cvt_pk_f32_fp8((int)(uu), false);           \
      f32x2 f1 = __builtin_amdgcn_cvt_pk_f32_fp8((int)(uu), true);            \
      acc2[2 * q]     = __builtin_elementwise_fma(wv, f0, acc2[2 * q]);       \
      acc2[2 * q + 1] = __builtin_elementwise_fma(wv, f1, acc2[2 * q + 1]);   \
    }
  int p = beg + g;
  for (; p + 4 < end; p += 8) {
    int s0 = esrc[p], s1 = esrc[p + 4];
    float lg0 = el[s0 * NHEAD + h] + ern;
    float lg1 = el[s1 * NHEAD + h] + ern;
    lg0 = (lg0 > 0.f) ? lg0 : 0.2f * lg0;
    lg1 = (lg1 > 0.f) ? lg1 : 0.2f * lg1;
    float w0 = __expf(lg0), w1 = __expf(lg1);
    dn += w0 + w1;
    f32x2 wv0 = {w0, w0}, wv1 = {w1, w1};
    uint4 u0 = *(const uint4*)(featf8 + (size_t)s0 * HD + l * 16);
    uint4 u1 = *(const uint4*)(featf8 + (size_t)s1 * HD + l * 16);
    DEC8(u0.x, 0, wv0) DEC8(u0.y, 1, wv0) DEC8(u0.z, 2, wv0) DEC8(u0.w, 3, wv0)
    DEC8(u1.x, 0, wv1) DEC8(u1.y, 1, wv1) DEC8(u1.z, 2, wv1) DEC8(u1.w, 3, wv1)
  }
  if (p < end) {
    int s0 = esrc[p];
    float lg0 = el[s0 * NHEAD + h] + ern;
    lg0 = (lg0 > 0.f) ? lg0 : 0.2f * lg0;
    float w0 = __expf(lg0);
    dn += w0;
    f32x2 wv0 = {w0, w0};
    uint4 u0 = *(const uint4*)(featf8 + (size_t)s0 * HD + l * 16);
    DEC8(u0.x, 0, wv0) DEC8(u0.y, 1, wv0) DEC8(u0.z, 2, wv0) DEC8(u0.w, 3, wv0)
  }
#undef DEC8
  dn += __shfl_xor(dn, 16);
  dn += __shfl_xor(dn, 32);
  float accs[16];
#pragma unroll
  for (int j = 0; j < 16; ++j) {
    float s = acc2[j >> 1][j & 1];
    s += __shfl_xor(s, 16);
    s += __shfl_xor(s, 32);
    accs[j] = s;
  }

  bool has = (end > beg);
  ushort rv[16];
  *(uint4*)&rv[0] = *(const uint4*)&rrb[(size_t)n * HD + l * 16];
  *(uint4*)&rv[8] = *(const uint4*)&rrb[(size_t)n * HD + l * 16 + 8];
  float vres[16];
  float inv = has ? 1.f / dn : 0.f;
#pragma unroll
  for (int j = 0; j < 16; ++j) {
    float v = accs[j] * inv + bf2f(rv[j]);
    vres[j] = (v > 0.f) ? v : (__expf(v) - 1.f);   // elu
  }

  if (!last) {
    if (g == 0) {
      ushort o[16];
#pragma unroll
      for (int j = 0; j < 16; ++j) o[j] = f2bf(vres[j]);
      *(uint4*)&hnext[(size_t)n * LDH + l * 16] = *(uint4*)&o[0];
      *(uint4*)&hnext[(size_t)n * LDH + l * 16 + 8] = *(uint4*)&o[8];
      if (l < 2) {
        ushort o2[16];
#pragma unroll
        for (int j = 0; j < 16; ++j) o2[j] = f2bf(pe[n * PDIM + l * 16 + j]);
        *(uint4*)&hnext[(size_t)n * LDH + HD + l * 16] = *(uint4*)&o2[0];
        *(uint4*)&hnext[(size_t)n * LDH + HD + l * 16 + 8] = *(uint4*)&o2[8];
      }
    }
  } else {
#pragma unroll
    for (int j = 0; j < 16; ++j) {
      vres[j] += __shfl_xor(vres[j], 4);
      vres[j] += __shfl_xor(vres[j], 8);
      vres[j] *= 0.25f;
    }
    if (g == 0 && l < 4) {
#pragma unroll
      for (int q = 0; q < 4; ++q)
        *(float4*)&out[(size_t)n * DHEAD + l * 16 + q * 4] =
            make_float4(vres[q * 4], vres[q * 4 + 1], vres[q * 4 + 2], vres[q * 4 + 3]);
    }
    if (g == 0 && l >= 4 && l < 6) {
      int c0 = (l - 4) * 16;
#pragma unroll
      for (int q = 0; q < 4; ++q) {
        const float* ps = &pe[n * PDIM + c0 + q * 4];
        *(float4*)&out[(size_t)Nn * DHEAD + (size_t)n * PDIM + c0 + q * 4] =
            make_float4(ps[0], ps[1], ps[2], ps[3]);
      }
    }
  }
}

extern "C" void kernel_launch(void* const* d_in, const int* in_sizes, int n_in,
                              void* d_out, int out_size, void* d_ws, size_t ws_size,
                              hipStream_t stream) {
  const float* fvs = (const float*)d_in[0];
  const float* pe  = (const float*)d_in[1];
  const int* src = (const int*)d_in[2];
  const int* dst = (const int*)d_in[3];
  const float* W[3]  = {(const float*)d_in[4], (const float*)d_in[8],  (const float*)d_in[12]};
  const float* al[3] = {(const float*)d_in[5], (const float*)d_in[9],  (const float*)d_in[13]};
  const float* ar[3] = {(const float*)d_in[6], (const float*)d_in[10], (const float*)d_in[14]};
  const float* rW[3] = {(const float*)d_in[7], (const float*)d_in[11], (const float*)d_in[15]};
  int Nn = in_sizes[0] / 128;
  int E  = in_sizes[2];
  int Ks[3] = {160, 288, 288};
  int nb1 = (Nn + 1 + 255) / 256;   // scan covers Nn+1 elements

  char* ws = (char*)d_ws;
  size_t off = 0;
  auto alloc = [&](size_t bytes) {
    void* p = ws + off;
    off += (bytes + 255) & ~(size_t)255;
    return p;
  };
  ushort* hbuf  = (ushort*)alloc((size_t)Nn * LDH * 2);
  unsigned char* featf8 = (unsigned char*)alloc((size_t)Nn * HD);
  ushort* rrb = (ushort*)alloc((size_t)Nn * HD * 2);
  float* el   = (float*)alloc((size_t)Nn * NHEAD * 4);
  float* er   = (float*)alloc((size_t)Nn * NHEAD * 4);
  PackArgs pa;
  int kbs[6] = {5, 5, 9, 9, 9, 9};
  pa.kboff[0] = 0;
  for (int m = 0; m < 6; ++m) pa.kboff[m + 1] = pa.kboff[m] + kbs[m];
  pa.W[0] = W[0]; pa.W[1] = rW[0]; pa.W[2] = W[1]; pa.W[3] = rW[1]; pa.W[4] = W[2]; pa.W[5] = rW[2];
  pa.al[0] = al[0]; pa.al[1] = nullptr; pa.al[2] = al[1]; pa.al[3] = nullptr; pa.al[4] = al[2]; pa.al[5] = nullptr;
  pa.ar[0] = ar[0]; pa.ar[1] = nullptr; pa.ar[2] = ar[1]; pa.ar[3] = nullptr; pa.ar[4] = ar[2]; pa.ar[5] = nullptr;
  ushort* Bp = (ushort*)alloc((size_t)pa.kboff[6] * NCB * 64 * 8 * 2);
  int* counts4   = (int*)alloc((size_t)Nn * 4 * 4);
  int4* sbase    = (int4*)alloc((size_t)Nn * 16);
  int* rank      = (int*)alloc((size_t)E * 4);
  int* excl      = (int*)alloc((size_t)(Nn + 1) * 4);
  int* bsum      = (int*)alloc((size_t)256 * 4);
  int* esrc      = (int*)alloc((size_t)E * 4);

  hipMemsetAsync(counts4, 0, (size_t)Nn * 16, stream);
  int nbCnt = (E + 1023) / 1024;    // 4 edges per thread, grid-stride
  int nbH0 = (Nn * 20 + 255) / 256;
  int nbPk = (pa.kboff[6] * NCB * 64 + 255) / 256;
  k_prep<<<nbCnt + nbH0 + nbPk, 256, 0, stream>>>(fvs, pe, hbuf, Nn, nbCnt, nbH0,
                                                  pa, Bp, dst, counts4, rank, E);
  k_scan1<<<nb1, 256, 0, stream>>>((const int4*)counts4, sbase, excl, bsum, Nn);
  k_scan2<<<1, 256, 0, stream>>>(bsum, nb1);

  float* out = (float*)d_out;
  int gb = (Nn + 63) / 64;
  int nbScat = (E + 255) / 256;
  int nbSc = (nbScat + 1) / 2;      // scatter blocks per grid.y half
  for (int L = 0; L < 3; ++L) {
    const ushort* BpW  = Bp + (size_t)pa.kboff[2 * L] * NCB * 64 * 8;
    const ushort* BprW = Bp + (size_t)pa.kboff[2 * L + 1] * NCB * 64 * 8;
    dim3 g(L == 0 ? gb + nbSc : gb, 2);
    if (Ks[L] == 160)
      k_gemm<5><<<g, 256, 0, stream>>>(hbuf, BpW, BprW, featf8, rrb, el, er, Nn, gb,
                                       src, dst, rank, excl, bsum, sbase, esrc, E);
    else
      k_gemm<9><<<g, 256, 0, stream>>>(hbuf, BpW, BprW, featf8, rrb, el, er, Nn, gb,
                                       src, dst, rank, excl, bsum, sbase, esrc, E);
    int last = (L == 2) ? 1 : 0;
    k_agg<<<(Nn + 3) / 4, 256, 0, stream>>>(esrc, excl, bsum, el, er, featf8, rrb, pe,
                                            hbuf, out, last, Nn);
  }
}